// Round 1
// baseline (2989.511 us; speedup 1.0000x reference)
//
#include <hip/hip_runtime.h>
#include <math.h>

// ws layout: [0, 4N)   deg (int)  -- later aliased as acc (float)
//            [4N, 8N)  s   (float)
//            [8N,12N)  dinv(float)

__global__ void zero_kernel(int* __restrict__ p, int n) {
    int i = blockIdx.x * blockDim.x + threadIdx.x;
    if (i < n) p[i] = 0;
}

__global__ void deg_kernel(const int* __restrict__ dst, int* __restrict__ deg, int E) {
    int i = (blockIdx.x * blockDim.x + threadIdx.x) * 4;
    if (i + 3 < E) {
        int4 d = *reinterpret_cast<const int4*>(dst + i);
        atomicAdd(&deg[d.x], 1);
        atomicAdd(&deg[d.y], 1);
        atomicAdd(&deg[d.z], 1);
        atomicAdd(&deg[d.w], 1);
    } else {
        for (int k = i; k < E; ++k) atomicAdd(&deg[dst[k]], 1);
    }
}

// dinv[i] = rsqrt(deg[i]+1); s[i] = x[i]*W*dinv[i]; acc[i] = s[i] (self-loop).
// acc aliases deg: thread i reads deg[i] before writing acc[i]; no cross-thread hazard.
__global__ void node_kernel(const float* __restrict__ x, const int* __restrict__ deg,
                            const float* __restrict__ W,
                            float* __restrict__ s, float* __restrict__ dinv,
                            float* __restrict__ acc, int N) {
    int i = blockIdx.x * blockDim.x + threadIdx.x;
    if (i < N) {
        float W0 = W[0];                       // scalar load, wave-uniform
        float di = rsqrtf((float)(deg[i] + 1));
        float si = x[i] * W0 * di;
        dinv[i] = di;
        s[i]    = si;
        acc[i]  = si;
    }
}

__global__ void scatter_kernel(const int* __restrict__ src, const int* __restrict__ dst,
                               const float* __restrict__ s, float* __restrict__ acc, int E) {
    int i = (blockIdx.x * blockDim.x + threadIdx.x) * 4;
    if (i + 3 < E) {
        int4 sv = *reinterpret_cast<const int4*>(src + i);
        int4 dv = *reinterpret_cast<const int4*>(dst + i);
        float a = s[sv.x];
        float b = s[sv.y];
        float c = s[sv.z];
        float d = s[sv.w];
        atomicAdd(&acc[dv.x], a);
        atomicAdd(&acc[dv.y], b);
        atomicAdd(&acc[dv.z], c);
        atomicAdd(&acc[dv.w], d);
    } else {
        for (int k = i; k < E; ++k) atomicAdd(&acc[dst[k]], s[src[k]]);
    }
}

__global__ void out_kernel(const float* __restrict__ acc, const float* __restrict__ dinv,
                           const float* __restrict__ b, float* __restrict__ out, int N) {
    int i = blockIdx.x * blockDim.x + threadIdx.x;
    if (i < N) {
        float z = dinv[i] * acc[i] + b[0];
        out[i] = 1.0f / (1.0f + expf(-z));
    }
}

extern "C" void kernel_launch(void* const* d_in, const int* in_sizes, int n_in,
                              void* d_out, int out_size, void* d_ws, size_t ws_size,
                              hipStream_t stream) {
    const int N = in_sizes[0];          // x is [N,1]
    const int E = in_sizes[1] / 2;      // edge_index is [2,E]
    const float* x  = (const float*)d_in[0];
    const int*   ei = (const int*)d_in[1];
    const float* W  = (const float*)d_in[2];
    const float* b  = (const float*)d_in[3];
    float* out = (float*)d_out;

    char* ws = (char*)d_ws;
    int*   deg  = (int*)ws;
    float* s    = (float*)(ws + (size_t)N * 4);
    float* dinv = (float*)(ws + (size_t)N * 8);
    float* acc  = (float*)deg;          // alias, see node_kernel comment

    const int* srcp = ei;
    const int* dstp = ei + E;

    const int T = 256;
    const int blocksN = (N + T - 1) / T;
    const int blocksE = ((E + 3) / 4 + T - 1) / T;

    zero_kernel<<<blocksN, T, 0, stream>>>(deg, N);
    deg_kernel<<<blocksE, T, 0, stream>>>(dstp, deg, E);
    node_kernel<<<blocksN, T, 0, stream>>>(x, deg, W, s, dinv, acc, N);
    scatter_kernel<<<blocksE, T, 0, stream>>>(srcp, dstp, s, acc, E);
    out_kernel<<<blocksN, T, 0, stream>>>(acc, dinv, b, out, N);
}